// Round 10
// baseline (599.233 us; speedup 1.0000x reference)
//
#include <hip/hip_runtime.h>

#define NEG_SLOPE 0.2f
#define NG 8
#define CH 64   // edge chunk per wave (lane-parallel weight phase)

typedef unsigned short ushort_t;

__device__ __forceinline__ float lrelu(float x) { return x > 0.f ? x : NEG_SLOPE * x; }
__device__ __forceinline__ float eluf(float x) { return x > 0.f ? x : expm1f(x); }
__device__ __forceinline__ float wave_sum(float v) {
    #pragma unroll
    for (int o = 32; o; o >>= 1) v += __shfl_xor(v, o);
    return v;
}
// f32 <-> bf16 (RNE), finite inputs only
__device__ __forceinline__ ushort_t f2bf(float f) {
    unsigned u = __float_as_uint(f);
    unsigned r = (u + 0x7FFFu + ((u >> 16) & 1u)) >> 16;
    return (ushort_t)r;
}
__device__ __forceinline__ float bf2f(ushort_t s) {
    return __uint_as_float(((unsigned)s) << 16);
}

// ---------------- CSR build ----------------------------------------------------
__global__ __launch_bounds__(256) void k_hist(const int* __restrict__ ei,
                                              int* __restrict__ deg, int E) {
    int e = blockIdx.x * 256 + threadIdx.x;
    if (e < E) atomicAdd(&deg[ei[E + e]], 1);
}

__global__ __launch_bounds__(256) void k_scanA(const int* __restrict__ deg,
                                               int* __restrict__ bsum, int N) {
    __shared__ int wsums[4];
    int b = blockIdx.x, t = threadIdx.x;
    int base = b * 1024 + t * 4;
    int s = 0;
    #pragma unroll
    for (int k = 0; k < 4; k++) { int i = base + k; if (i < N) s += deg[i]; }
    #pragma unroll
    for (int o = 32; o; o >>= 1) s += __shfl_xor(s, o);
    if ((t & 63) == 0) wsums[t >> 6] = s;
    __syncthreads();
    if (t == 0) bsum[b] = wsums[0] + wsums[1] + wsums[2] + wsums[3];
}

__global__ __launch_bounds__(64) void k_scanB(const int* __restrict__ bsum,
                                              int* __restrict__ boff,
                                              int* __restrict__ rpN, int SB) {
    int lane = threadIdx.x;
    int own = (lane < SB) ? bsum[lane] : 0;
    int v = own;
    #pragma unroll
    for (int o = 1; o < 64; o <<= 1) { int y = __shfl_up(v, o); if (lane >= o) v += y; }
    if (lane < SB) boff[lane] = v - own;
    if (lane == 63) *rpN = v;
}

__global__ __launch_bounds__(256) void k_scanC(const int* __restrict__ deg,
                                               const int* __restrict__ boff,
                                               int* __restrict__ rp,
                                               int* __restrict__ cur, int N) {
    __shared__ int wtot[4];
    int b = blockIdx.x, t = threadIdx.x;
    int wid = t >> 6, lane = t & 63;
    int base = b * 1024 + t * 4;
    int d[4];
    #pragma unroll
    for (int k = 0; k < 4; k++) d[k] = (base + k < N) ? deg[base + k] : 0;
    int tsum = d[0] + d[1] + d[2] + d[3];
    int v = tsum;
    #pragma unroll
    for (int o = 1; o < 64; o <<= 1) { int y = __shfl_up(v, o); if (lane >= o) v += y; }
    if (lane == 63) wtot[wid] = v;
    __syncthreads();
    int wbase = 0;
    for (int k = 0; k < wid; k++) wbase += wtot[k];
    int run = boff[b] + wbase + v - tsum;
    #pragma unroll
    for (int k = 0; k < 4; k++) {
        if (base + k < N) { rp[base + k] = run; cur[base + k] = run; }
        run += d[k];
    }
}

__global__ __launch_bounds__(256) void k_fill(const int* __restrict__ ei,
                                              int* __restrict__ cur,
                                              int* __restrict__ csr, int E) {
    int e = blockIdx.x * 256 + threadIdx.x;
    if (e >= E) return;
    int s = ei[e], d = ei[E + e];
    int pos = atomicAdd(&cur[d], 1);
    csr[pos] = s;
}

// ------- GEMM1: xw1(bf16, head-interleaved [k*4+h]) = x @ W1 + al/ar epilogue ---
__global__ __launch_bounds__(256) void k_gemm1(const float* __restrict__ x,
                                               const float* __restrict__ W1,
                                               const float* __restrict__ a_s,
                                               const float* __restrict__ a_d,
                                               ushort_t* __restrict__ xw1b,
                                               float* __restrict__ al4,
                                               float* __restrict__ ar4, int N) {
    __shared__ float As[16][256];   // 16 KB; reused as ushort[16][256] for repack
    int r0 = blockIdx.x * 16;
    int lane = threadIdx.x & 63, rq = threadIdx.x >> 6;
    int c4 = lane << 2;
    for (int i = threadIdx.x; i < 1024; i += 256) {
        int r = i >> 6, k4 = (i & 63) << 2;
        float4 v = (r0 + r < N) ? *(const float4*)(x + (size_t)(r0 + r) * 256 + k4)
                                : make_float4(0.f, 0.f, 0.f, 0.f);
        As[r][k4] = v.x; As[r][k4 + 1] = v.y; As[r][k4 + 2] = v.z; As[r][k4 + 3] = v.w;
    }
    __syncthreads();
    float4 acc[4];
    #pragma unroll
    for (int t = 0; t < 4; t++) acc[t] = make_float4(0.f, 0.f, 0.f, 0.f);
    for (int k4 = 0; k4 < 256; k4 += 4) {
        float4 w0 = *(const float4*)(W1 + (size_t)(k4 + 0) * 256 + c4);
        float4 w1 = *(const float4*)(W1 + (size_t)(k4 + 1) * 256 + c4);
        float4 w2 = *(const float4*)(W1 + (size_t)(k4 + 2) * 256 + c4);
        float4 w3 = *(const float4*)(W1 + (size_t)(k4 + 3) * 256 + c4);
        #pragma unroll
        for (int t = 0; t < 4; t++) {
            float4 a = *(const float4*)(&As[rq + 4 * t][k4]);
            acc[t].x += a.x * w0.x + a.y * w1.x + a.z * w2.x + a.w * w3.x;
            acc[t].y += a.x * w0.y + a.y * w1.y + a.z * w2.y + a.w * w3.y;
            acc[t].z += a.x * w0.z + a.y * w1.z + a.z * w2.z + a.w * w3.z;
            acc[t].w += a.x * w0.w + a.y * w1.w + a.z * w2.w + a.w * w3.w;
        }
    }
    // fused al/ar from exact f32 acc: head h = lane>>4, cols kk..kk+3
    int h = lane >> 4, kk = c4 & 63;
    float4 s4 = *(const float4*)(a_s + h * 64 + kk);
    float4 d4 = *(const float4*)(a_d + h * 64 + kk);
    #pragma unroll
    for (int t = 0; t < 4; t++) {
        float sl = acc[t].x * s4.x + acc[t].y * s4.y + acc[t].z * s4.z + acc[t].w * s4.w;
        float sr = acc[t].x * d4.x + acc[t].y * d4.y + acc[t].z * d4.z + acc[t].w * d4.w;
        #pragma unroll
        for (int o = 1; o < 16; o <<= 1) { sl += __shfl_xor(sl, o); sr += __shfl_xor(sr, o); }
        int r = r0 + rq + 4 * t;
        if ((lane & 15) == 0 && r < N) {
            al4[(size_t)r * 4 + h] = sl;
            ar4[(size_t)r * 4 + h] = sr;
        }
    }
    // repack to head-interleaved bf16 via LDS, then coalesced stores
    __syncthreads();                       // all waves done reading As
    ushort_t* Ls = (ushort_t*)As;          // [16][256] ushorts = 8 KB
    #pragma unroll
    for (int t = 0; t < 4; t++) {
        int rl = rq + 4 * t;
        Ls[rl * 256 + (kk + 0) * 4 + h] = f2bf(acc[t].x);
        Ls[rl * 256 + (kk + 1) * 4 + h] = f2bf(acc[t].y);
        Ls[rl * 256 + (kk + 2) * 4 + h] = f2bf(acc[t].z);
        Ls[rl * 256 + (kk + 3) * 4 + h] = f2bf(acc[t].w);
    }
    __syncthreads();
    #pragma unroll
    for (int p = 0; p < 2; p++) {
        int flat = p * 2048 + threadIdx.x * 8;     // 8 ushorts = 16 B per thread
        int rl = flat >> 8, col = flat & 255;
        int r = r0 + rl;
        if (r < N)
            *(uint4*)(xw1b + (size_t)r * 256 + col) = *(const uint4*)(Ls + flat);
    }
}

__device__ __forceinline__ float4 wexp4(float4 a, float4 arn) {
    float4 w;
    w.x = __expf(lrelu(a.x + arn.x));
    w.y = __expf(lrelu(a.y + arn.y));
    w.z = __expf(lrelu(a.z + arn.z));
    w.w = __expf(lrelu(a.w + arn.w));
    return w;
}

// ------- layer-1 aggregate: two-phase, 8-deep gather pipeline -------------------
__global__ __launch_bounds__(256) void k_agg4(const int* __restrict__ rp,
                                              const int* __restrict__ csr,
                                              const float* __restrict__ al4,
                                              const float* __restrict__ ar4,
                                              const ushort_t* __restrict__ xw1b,
                                              const float* __restrict__ b1,
                                              const float* __restrict__ W2,
                                              const float* __restrict__ as2,
                                              const float* __restrict__ ad2,
                                              ushort_t* __restrict__ xw2b,
                                              float* __restrict__ al2,
                                              float* __restrict__ ar2, int N) {
    __shared__ float hs[4][256];
    __shared__ float4 wbuf[4][CH];
    __shared__ int sbuf[4][CH];
    int wIdx = threadIdx.x >> 6;
    int n = (blockIdx.x * 256 + threadIdx.x) >> 6;
    int lane = threadIdx.x & 63;
    bool act = n < N;
    if (act) {
        int e0 = rp[n], e1 = rp[n + 1];
        float4 arn = *(const float4*)(ar4 + (size_t)n * 4);
        float4 aln = *(const float4*)(al4 + (size_t)n * 4);
        float4 wsf = wexp4(aln, arn);           // self-loop weight
        ushort4 sv = *(const ushort4*)(xw1b + (size_t)n * 256 + lane * 4);
        float a0 = wsf.x * bf2f(sv.x);
        float a1 = wsf.y * bf2f(sv.y);
        float a2 = wsf.z * bf2f(sv.z);
        float a3 = wsf.w * bf2f(sv.w);
        float px = 0.f, py = 0.f, pz = 0.f, pw = 0.f;   // lane-partial weight sums
        for (int cs = e0; cs < e1; cs += CH) {
            int cnt = min(CH, e1 - cs);
            if (lane < cnt) {
                int s = csr[cs + lane];
                float4 A = *(const float4*)(al4 + (size_t)s * 4);
                float4 w = wexp4(A, arn);
                sbuf[wIdx][lane] = s;
                wbuf[wIdx][lane] = w;
                px += w.x; py += w.y; pz += w.z; pw += w.w;
            }
            // drain LDS writes; per-wave LDS is in-order, no block barrier needed
            asm volatile("s_waitcnt lgkmcnt(0)" ::: "memory");
            int jj = 0;
            for (; jj + 8 <= cnt; jj += 8) {
                int s0 = sbuf[wIdx][jj],     s1 = sbuf[wIdx][jj + 1];
                int s2 = sbuf[wIdx][jj + 2], s3 = sbuf[wIdx][jj + 3];
                int s4_ = sbuf[wIdx][jj + 4], s5 = sbuf[wIdx][jj + 5];
                int s6 = sbuf[wIdx][jj + 6], s7 = sbuf[wIdx][jj + 7];
                ushort4 v0 = *(const ushort4*)(xw1b + (size_t)s0 * 256 + lane * 4);
                ushort4 v1 = *(const ushort4*)(xw1b + (size_t)s1 * 256 + lane * 4);
                ushort4 v2 = *(const ushort4*)(xw1b + (size_t)s2 * 256 + lane * 4);
                ushort4 v3 = *(const ushort4*)(xw1b + (size_t)s3 * 256 + lane * 4);
                ushort4 v4 = *(const ushort4*)(xw1b + (size_t)s4_ * 256 + lane * 4);
                ushort4 v5 = *(const ushort4*)(xw1b + (size_t)s5 * 256 + lane * 4);
                ushort4 v6 = *(const ushort4*)(xw1b + (size_t)s6 * 256 + lane * 4);
                ushort4 v7 = *(const ushort4*)(xw1b + (size_t)s7 * 256 + lane * 4);
                float4 w0 = wbuf[wIdx][jj],     w1 = wbuf[wIdx][jj + 1];
                float4 w2 = wbuf[wIdx][jj + 2], w3 = wbuf[wIdx][jj + 3];
                float4 w4 = wbuf[wIdx][jj + 4], w5 = wbuf[wIdx][jj + 5];
                float4 w6 = wbuf[wIdx][jj + 6], w7 = wbuf[wIdx][jj + 7];
                a0 += w0.x * bf2f(v0.x) + w1.x * bf2f(v1.x) + w2.x * bf2f(v2.x) + w3.x * bf2f(v3.x)
                    + w4.x * bf2f(v4.x) + w5.x * bf2f(v5.x) + w6.x * bf2f(v6.x) + w7.x * bf2f(v7.x);
                a1 += w0.y * bf2f(v0.y) + w1.y * bf2f(v1.y) + w2.y * bf2f(v2.y) + w3.y * bf2f(v3.y)
                    + w4.y * bf2f(v4.y) + w5.y * bf2f(v5.y) + w6.y * bf2f(v6.y) + w7.y * bf2f(v7.y);
                a2 += w0.z * bf2f(v0.z) + w1.z * bf2f(v1.z) + w2.z * bf2f(v2.z) + w3.z * bf2f(v3.z)
                    + w4.z * bf2f(v4.z) + w5.z * bf2f(v5.z) + w6.z * bf2f(v6.z) + w7.z * bf2f(v7.z);
                a3 += w0.w * bf2f(v0.w) + w1.w * bf2f(v1.w) + w2.w * bf2f(v2.w) + w3.w * bf2f(v3.w)
                    + w4.w * bf2f(v4.w) + w5.w * bf2f(v5.w) + w6.w * bf2f(v6.w) + w7.w * bf2f(v7.w);
            }
            for (; jj + 4 <= cnt; jj += 4) {
                int s0 = sbuf[wIdx][jj],     s1 = sbuf[wIdx][jj + 1];
                int s2 = sbuf[wIdx][jj + 2], s3 = sbuf[wIdx][jj + 3];
                ushort4 v0 = *(const ushort4*)(xw1b + (size_t)s0 * 256 + lane * 4);
                ushort4 v1 = *(const ushort4*)(xw1b + (size_t)s1 * 256 + lane * 4);
                ushort4 v2 = *(const ushort4*)(xw1b + (size_t)s2 * 256 + lane * 4);
                ushort4 v3 = *(const ushort4*)(xw1b + (size_t)s3 * 256 + lane * 4);
                float4 w0 = wbuf[wIdx][jj],     w1 = wbuf[wIdx][jj + 1];
                float4 w2 = wbuf[wIdx][jj + 2], w3 = wbuf[wIdx][jj + 3];
                a0 += w0.x * bf2f(v0.x) + w1.x * bf2f(v1.x) + w2.x * bf2f(v2.x) + w3.x * bf2f(v3.x);
                a1 += w0.y * bf2f(v0.y) + w1.y * bf2f(v1.y) + w2.y * bf2f(v2.y) + w3.y * bf2f(v3.y);
                a2 += w0.z * bf2f(v0.z) + w1.z * bf2f(v1.z) + w2.z * bf2f(v2.z) + w3.z * bf2f(v3.z);
                a3 += w0.w * bf2f(v0.w) + w1.w * bf2f(v1.w) + w2.w * bf2f(v2.w) + w3.w * bf2f(v3.w);
            }
            for (; jj < cnt; jj++) {
                int s = sbuf[wIdx][jj];
                float4 w = wbuf[wIdx][jj];
                ushort4 v = *(const ushort4*)(xw1b + (size_t)s * 256 + lane * 4);
                a0 += w.x * bf2f(v.x);
                a1 += w.y * bf2f(v.y);
                a2 += w.z * bf2f(v.z);
                a3 += w.w * bf2f(v.w);
            }
        }
        float wx = wave_sum(px) + wsf.x;
        float wy = wave_sum(py) + wsf.y;
        float wz = wave_sum(pz) + wsf.z;
        float ww = wave_sum(pw) + wsf.w;
        hs[wIdx][lane]       = eluf(a0 / wx + b1[lane]);
        hs[wIdx][64 + lane]  = eluf(a1 / wy + b1[64 + lane]);
        hs[wIdx][128 + lane] = eluf(a2 / wz + b1[128 + lane]);
        hs[wIdx][192 + lane] = eluf(a3 / ww + b1[192 + lane]);
    }
    __syncthreads();
    if (act) {
        float acc2 = 0.f;
        #pragma unroll 4
        for (int k = 0; k < 256; k++)
            acc2 += hs[wIdx][k] * W2[(size_t)k * 64 + lane];
        xw2b[(size_t)n * 64 + lane] = f2bf(acc2);
        float sl = wave_sum(acc2 * as2[lane]);
        float sr = wave_sum(acc2 * ad2[lane]);
        if (lane == 0) { al2[n] = sl; ar2[n] = sr; }
    }
}

// ------- layer-2 aggregate: two-phase, 8-deep gather, bf16 rows -----------------
__global__ __launch_bounds__(256) void k_agg2(const int* __restrict__ rp,
                                              const int* __restrict__ csr,
                                              const float* __restrict__ al2,
                                              const float* __restrict__ ar2,
                                              const ushort_t* __restrict__ xw2b,
                                              const float* __restrict__ b2,
                                              float* __restrict__ hout, int N) {
    __shared__ float wbuf[4][CH];
    __shared__ int sbuf[4][CH];
    int wIdx = threadIdx.x >> 6;
    int n = (blockIdx.x * 256 + threadIdx.x) >> 6;
    int lane = threadIdx.x & 63;
    if (n >= N) return;
    int e0 = rp[n], e1 = rp[n + 1];
    float arn = ar2[n];
    float wself = __expf(lrelu(al2[n] + arn));
    float acc = wself * bf2f(xw2b[(size_t)n * 64 + lane]);
    float p = 0.f;
    for (int cs = e0; cs < e1; cs += CH) {
        int cnt = min(CH, e1 - cs);
        if (lane < cnt) {
            int s = csr[cs + lane];
            float w = __expf(lrelu(al2[s] + arn));
            sbuf[wIdx][lane] = s;
            wbuf[wIdx][lane] = w;
            p += w;
        }
        asm volatile("s_waitcnt lgkmcnt(0)" ::: "memory");
        int jj = 0;
        for (; jj + 8 <= cnt; jj += 8) {
            int s0 = sbuf[wIdx][jj],     s1 = sbuf[wIdx][jj + 1];
            int s2 = sbuf[wIdx][jj + 2], s3 = sbuf[wIdx][jj + 3];
            int s4_ = sbuf[wIdx][jj + 4], s5 = sbuf[wIdx][jj + 5];
            int s6 = sbuf[wIdx][jj + 6], s7 = sbuf[wIdx][jj + 7];
            float v0 = bf2f(xw2b[(size_t)s0 * 64 + lane]);
            float v1 = bf2f(xw2b[(size_t)s1 * 64 + lane]);
            float v2 = bf2f(xw2b[(size_t)s2 * 64 + lane]);
            float v3 = bf2f(xw2b[(size_t)s3 * 64 + lane]);
            float v4 = bf2f(xw2b[(size_t)s4_ * 64 + lane]);
            float v5 = bf2f(xw2b[(size_t)s5 * 64 + lane]);
            float v6 = bf2f(xw2b[(size_t)s6 * 64 + lane]);
            float v7 = bf2f(xw2b[(size_t)s7 * 64 + lane]);
            float w0 = wbuf[wIdx][jj],     w1 = wbuf[wIdx][jj + 1];
            float w2 = wbuf[wIdx][jj + 2], w3 = wbuf[wIdx][jj + 3];
            float w4 = wbuf[wIdx][jj + 4], w5 = wbuf[wIdx][jj + 5];
            float w6 = wbuf[wIdx][jj + 6], w7 = wbuf[wIdx][jj + 7];
            acc += w0 * v0 + w1 * v1 + w2 * v2 + w3 * v3
                 + w4 * v4 + w5 * v5 + w6 * v6 + w7 * v7;
        }
        for (; jj + 4 <= cnt; jj += 4) {
            int s0 = sbuf[wIdx][jj],     s1 = sbuf[wIdx][jj + 1];
            int s2 = sbuf[wIdx][jj + 2], s3 = sbuf[wIdx][jj + 3];
            float v0 = bf2f(xw2b[(size_t)s0 * 64 + lane]);
            float v1 = bf2f(xw2b[(size_t)s1 * 64 + lane]);
            float v2 = bf2f(xw2b[(size_t)s2 * 64 + lane]);
            float v3 = bf2f(xw2b[(size_t)s3 * 64 + lane]);
            float w0 = wbuf[wIdx][jj],     w1 = wbuf[wIdx][jj + 1];
            float w2 = wbuf[wIdx][jj + 2], w3 = wbuf[wIdx][jj + 3];
            acc += w0 * v0 + w1 * v1 + w2 * v2 + w3 * v3;
        }
        for (; jj < cnt; jj++) {
            int s = sbuf[wIdx][jj];
            acc += wbuf[wIdx][jj] * bf2f(xw2b[(size_t)s * 64 + lane]);
        }
    }
    float wsum = wave_sum(p) + wself;
    hout[(size_t)n * 64 + lane] = eluf(acc / wsum + b2[lane]);
}

// ------- mean pool (batch sorted, 32 nodes/wave) + logits -----------------------
__global__ __launch_bounds__(256) void k_pool(const float* __restrict__ h2,
                                              const int* __restrict__ batch,
                                              float* __restrict__ pooled,
                                              float* __restrict__ cnt, int N) {
    int wave = (blockIdx.x * 256 + threadIdx.x) >> 6;
    int lane = threadIdx.x & 63;
    int n0 = wave * 32;
    if (n0 >= N) return;
    int n1 = min(n0 + 32, N);
    float acc = 0.f; int cl = 0;
    int curg = batch[n0];
    for (int n = n0; n < n1; n++) {
        int g = batch[n];
        if (g != curg) {
            atomicAdd(&pooled[curg * 64 + lane], acc);
            if (lane == 0) atomicAdd(&cnt[curg], (float)cl);
            acc = 0.f; cl = 0; curg = g;
        }
        acc += h2[(size_t)n * 64 + lane];
        cl++;
    }
    atomicAdd(&pooled[curg * 64 + lane], acc);
    if (lane == 0) atomicAdd(&cnt[curg], (float)cl);
}

__global__ __launch_bounds__(64) void k_logits(const float* __restrict__ pooled,
                                               const float* __restrict__ cnt,
                                               const float* __restrict__ fcW,
                                               const float* __restrict__ fcb,
                                               float* __restrict__ out) {
    int t = threadIdx.x;
    if (t >= NG * 2) return;
    int g = t >> 1, o = t & 1;
    float invc = 1.f / fmaxf(cnt[g], 1.f);
    float s = 0.f;
    for (int c = 0; c < 64; c++)
        s += pooled[g * 64 + c] * invc * fcW[c * 2 + o];
    s += fcb[o];
    out[g * 2 + o] = s;
}

extern "C" void kernel_launch(void* const* d_in, const int* in_sizes, int n_in,
                              void* d_out, int out_size, void* d_ws, size_t ws_size,
                              hipStream_t stream) {
    const float* x     = (const float*)d_in[0];
    const int*   ei    = (const int*)d_in[1];
    const int*   batch = (const int*)d_in[2];
    const float* W1    = (const float*)d_in[3];
    const float* as1   = (const float*)d_in[4];
    const float* ad1   = (const float*)d_in[5];
    const float* b1    = (const float*)d_in[6];
    const float* W2    = (const float*)d_in[7];
    const float* as2   = (const float*)d_in[8];
    const float* ad2   = (const float*)d_in[9];
    const float* b2v   = (const float*)d_in[10];
    const float* fcW   = (const float*)d_in[11];
    const float* fcb   = (const float*)d_in[12];
    float* out = (float*)d_out;

    const int N = in_sizes[2];       // 50000
    const int E = in_sizes[1] / 2;   // 800000
    const size_t nv  = (size_t)N * 64;
    const size_t nv4 = (size_t)N * 256;
    const int SB = (N + 1023) / 1024;

    // workspace layout: bf16 xw1, bf16 xw2, then floats, then ints (~36 MB)
    ushort_t* xw1b = (ushort_t*)d_ws;                      // nv4 ushorts (25.6 MB)
    ushort_t* xw2b   = xw1b + nv4;                         // nv ushorts (6.4 MB)
    float*    al4    = (float*)(xw2b + nv);                // N*4
    float*    ar4    = al4 + (size_t)N * 4;                // N*4
    float*    al2    = ar4 + (size_t)N * 4;                // N
    float*    ar2    = al2 + N;                            // N
    float*    pooled = ar2 + N;                            // 512
    float*    cnt    = pooled + NG * 64;                   // 8
    int*      deg    = (int*)(cnt + 8);                    // N
    int*      rp     = deg + N;                            // N+1
    int*      cur    = rp + N + 1;                         // N
    int*      csr    = cur + N;                            // E
    int*      bsum   = csr + E;                            // SB
    int*      boff   = bsum + 64;                          // SB

    const int gE  = (E + 255) / 256;
    const int gB4 = (N + 3) / 4;
    const int gG1 = (N + 15) / 16;
    const int pw  = (N + 31) / 32;
    const int gP  = (pw * 64 + 255) / 256;

    // ---- CSR build ----
    hipMemsetAsync(deg, 0, (size_t)N * sizeof(int), stream);
    k_hist<<<gE, 256, 0, stream>>>(ei, deg, E);
    k_scanA<<<SB, 256, 0, stream>>>(deg, bsum, N);
    k_scanB<<<1, 64, 0, stream>>>(bsum, boff, rp + N, SB);
    k_scanC<<<SB, 256, 0, stream>>>(deg, boff, rp, cur, N);
    k_fill<<<gE, 256, 0, stream>>>(ei, cur, csr, E);

    // ---- layer 1 ----
    k_gemm1<<<gG1, 256, 0, stream>>>(x, W1, as1, ad1, xw1b, al4, ar4, N);
    k_agg4<<<gB4, 256, 0, stream>>>(rp, csr, al4, ar4, xw1b, b1, W2, as2, ad2,
                                    xw2b, al2, ar2, N);

    // ---- layer 2 ----
    k_agg2<<<gB4, 256, 0, stream>>>(rp, csr, al2, ar2, xw2b, b2v, out, N);

    // ---- pooling + logits ----
    hipMemsetAsync(pooled, 0, (NG * 64 + NG) * sizeof(float), stream);
    k_pool<<<gP, 256, 0, stream>>>(out, batch, pooled, cnt, N);
    k_logits<<<1, 64, 0, stream>>>(pooled, cnt, fcW, fcb, out + nv);
}

// Round 11
// 553.739 us; speedup vs baseline: 1.0822x; 1.0822x over previous
//
#include <hip/hip_runtime.h>

#define NEG_SLOPE 0.2f
#define NG 8
#define CH 64   // edge chunk per wave (lane-parallel weight phase)

typedef unsigned short ushort_t;

__device__ __forceinline__ float lrelu(float x) { return x > 0.f ? x : NEG_SLOPE * x; }
__device__ __forceinline__ float eluf(float x) { return x > 0.f ? x : expm1f(x); }
__device__ __forceinline__ float wave_sum(float v) {
    #pragma unroll
    for (int o = 32; o; o >>= 1) v += __shfl_xor(v, o);
    return v;
}
// f32 <-> bf16 (RNE), finite inputs only
__device__ __forceinline__ ushort_t f2bf(float f) {
    unsigned u = __float_as_uint(f);
    unsigned r = (u + 0x7FFFu + ((u >> 16) & 1u)) >> 16;
    return (ushort_t)r;
}
__device__ __forceinline__ float bf2f(ushort_t s) {
    return __uint_as_float(((unsigned)s) << 16);
}

// ---------------- CSR build ----------------------------------------------------
__global__ __launch_bounds__(256) void k_hist(const int* __restrict__ ei,
                                              int* __restrict__ deg, int E) {
    int e = blockIdx.x * 256 + threadIdx.x;
    if (e < E) atomicAdd(&deg[ei[E + e]], 1);
}

__global__ __launch_bounds__(256) void k_scanA(const int* __restrict__ deg,
                                               int* __restrict__ bsum, int N) {
    __shared__ int wsums[4];
    int b = blockIdx.x, t = threadIdx.x;
    int base = b * 1024 + t * 4;
    int s = 0;
    #pragma unroll
    for (int k = 0; k < 4; k++) { int i = base + k; if (i < N) s += deg[i]; }
    #pragma unroll
    for (int o = 32; o; o >>= 1) s += __shfl_xor(s, o);
    if ((t & 63) == 0) wsums[t >> 6] = s;
    __syncthreads();
    if (t == 0) bsum[b] = wsums[0] + wsums[1] + wsums[2] + wsums[3];
}

__global__ __launch_bounds__(64) void k_scanB(const int* __restrict__ bsum,
                                              int* __restrict__ boff,
                                              int* __restrict__ rpN, int SB) {
    int lane = threadIdx.x;
    int own = (lane < SB) ? bsum[lane] : 0;
    int v = own;
    #pragma unroll
    for (int o = 1; o < 64; o <<= 1) { int y = __shfl_up(v, o); if (lane >= o) v += y; }
    if (lane < SB) boff[lane] = v - own;
    if (lane == 63) *rpN = v;
}

__global__ __launch_bounds__(256) void k_scanC(const int* __restrict__ deg,
                                               const int* __restrict__ boff,
                                               int* __restrict__ rp,
                                               int* __restrict__ cur, int N) {
    __shared__ int wtot[4];
    int b = blockIdx.x, t = threadIdx.x;
    int wid = t >> 6, lane = t & 63;
    int base = b * 1024 + t * 4;
    int d[4];
    #pragma unroll
    for (int k = 0; k < 4; k++) d[k] = (base + k < N) ? deg[base + k] : 0;
    int tsum = d[0] + d[1] + d[2] + d[3];
    int v = tsum;
    #pragma unroll
    for (int o = 1; o < 64; o <<= 1) { int y = __shfl_up(v, o); if (lane >= o) v += y; }
    if (lane == 63) wtot[wid] = v;
    __syncthreads();
    int wbase = 0;
    for (int k = 0; k < wid; k++) wbase += wtot[k];
    int run = boff[b] + wbase + v - tsum;
    #pragma unroll
    for (int k = 0; k < 4; k++) {
        if (base + k < N) { rp[base + k] = run; cur[base + k] = run; }
        run += d[k];
    }
}

__global__ __launch_bounds__(256) void k_fill(const int* __restrict__ ei,
                                              int* __restrict__ cur,
                                              int* __restrict__ csr, int E) {
    int e = blockIdx.x * 256 + threadIdx.x;
    if (e >= E) return;
    int s = ei[e], d = ei[E + e];
    int pos = atomicAdd(&cur[d], 1);
    csr[pos] = s;
}

// ------- GEMM1: xw1(bf16, head-interleaved [k*4+h]) = x @ W1 + al/ar epilogue ---
__global__ __launch_bounds__(256) void k_gemm1(const float* __restrict__ x,
                                               const float* __restrict__ W1,
                                               const float* __restrict__ a_s,
                                               const float* __restrict__ a_d,
                                               ushort_t* __restrict__ xw1b,
                                               float* __restrict__ al4,
                                               float* __restrict__ ar4, int N) {
    __shared__ float As[16][256];   // 16 KB; reused as ushort[16][256] for repack
    int r0 = blockIdx.x * 16;
    int lane = threadIdx.x & 63, rq = threadIdx.x >> 6;
    int c4 = lane << 2;
    for (int i = threadIdx.x; i < 1024; i += 256) {
        int r = i >> 6, k4 = (i & 63) << 2;
        float4 v = (r0 + r < N) ? *(const float4*)(x + (size_t)(r0 + r) * 256 + k4)
                                : make_float4(0.f, 0.f, 0.f, 0.f);
        As[r][k4] = v.x; As[r][k4 + 1] = v.y; As[r][k4 + 2] = v.z; As[r][k4 + 3] = v.w;
    }
    __syncthreads();
    float4 acc[4];
    #pragma unroll
    for (int t = 0; t < 4; t++) acc[t] = make_float4(0.f, 0.f, 0.f, 0.f);
    for (int k4 = 0; k4 < 256; k4 += 4) {
        float4 w0 = *(const float4*)(W1 + (size_t)(k4 + 0) * 256 + c4);
        float4 w1 = *(const float4*)(W1 + (size_t)(k4 + 1) * 256 + c4);
        float4 w2 = *(const float4*)(W1 + (size_t)(k4 + 2) * 256 + c4);
        float4 w3 = *(const float4*)(W1 + (size_t)(k4 + 3) * 256 + c4);
        #pragma unroll
        for (int t = 0; t < 4; t++) {
            float4 a = *(const float4*)(&As[rq + 4 * t][k4]);
            acc[t].x += a.x * w0.x + a.y * w1.x + a.z * w2.x + a.w * w3.x;
            acc[t].y += a.x * w0.y + a.y * w1.y + a.z * w2.y + a.w * w3.y;
            acc[t].z += a.x * w0.z + a.y * w1.z + a.z * w2.z + a.w * w3.z;
            acc[t].w += a.x * w0.w + a.y * w1.w + a.z * w2.w + a.w * w3.w;
        }
    }
    // fused al/ar from exact f32 acc: head h = lane>>4, cols kk..kk+3
    int h = lane >> 4, kk = c4 & 63;
    float4 s4 = *(const float4*)(a_s + h * 64 + kk);
    float4 d4 = *(const float4*)(a_d + h * 64 + kk);
    #pragma unroll
    for (int t = 0; t < 4; t++) {
        float sl = acc[t].x * s4.x + acc[t].y * s4.y + acc[t].z * s4.z + acc[t].w * s4.w;
        float sr = acc[t].x * d4.x + acc[t].y * d4.y + acc[t].z * d4.z + acc[t].w * d4.w;
        #pragma unroll
        for (int o = 1; o < 16; o <<= 1) { sl += __shfl_xor(sl, o); sr += __shfl_xor(sr, o); }
        int r = r0 + rq + 4 * t;
        if ((lane & 15) == 0 && r < N) {
            al4[(size_t)r * 4 + h] = sl;
            ar4[(size_t)r * 4 + h] = sr;
        }
    }
    // repack to head-interleaved bf16 via LDS, then coalesced stores
    __syncthreads();                       // all waves done reading As
    ushort_t* Ls = (ushort_t*)As;          // [16][256] ushorts = 8 KB
    #pragma unroll
    for (int t = 0; t < 4; t++) {
        int rl = rq + 4 * t;
        Ls[rl * 256 + (kk + 0) * 4 + h] = f2bf(acc[t].x);
        Ls[rl * 256 + (kk + 1) * 4 + h] = f2bf(acc[t].y);
        Ls[rl * 256 + (kk + 2) * 4 + h] = f2bf(acc[t].z);
        Ls[rl * 256 + (kk + 3) * 4 + h] = f2bf(acc[t].w);
    }
    __syncthreads();
    #pragma unroll
    for (int p = 0; p < 2; p++) {
        int flat = p * 2048 + threadIdx.x * 8;     // 8 ushorts = 16 B per thread
        int rl = flat >> 8, col = flat & 255;
        int r = r0 + rl;
        if (r < N)
            *(uint4*)(xw1b + (size_t)r * 256 + col) = *(const uint4*)(Ls + flat);
    }
}

__device__ __forceinline__ float4 wexp4(float4 a, float4 arn) {
    float4 w;
    w.x = __expf(lrelu(a.x + arn.x));
    w.y = __expf(lrelu(a.y + arn.y));
    w.z = __expf(lrelu(a.z + arn.z));
    w.w = __expf(lrelu(a.w + arn.w));
    return w;
}

// ------- layer-1 aggregate: two-phase, 4-deep gather (round-9 structure) --------
__global__ __launch_bounds__(256, 8) void k_agg4(const int* __restrict__ rp,
                                                 const int* __restrict__ csr,
                                                 const float* __restrict__ al4,
                                                 const float* __restrict__ ar4,
                                                 const ushort_t* __restrict__ xw1b,
                                                 const float* __restrict__ b1,
                                                 const float* __restrict__ W2,
                                                 const float* __restrict__ as2,
                                                 const float* __restrict__ ad2,
                                                 ushort_t* __restrict__ xw2b,
                                                 float* __restrict__ al2,
                                                 float* __restrict__ ar2, int N) {
    __shared__ float hs[4][256];
    __shared__ float4 wbuf[4][CH];
    __shared__ int sbuf[4][CH];
    int wIdx = threadIdx.x >> 6;
    int n = (blockIdx.x * 256 + threadIdx.x) >> 6;
    int lane = threadIdx.x & 63;
    bool act = n < N;
    if (act) {
        int e0 = rp[n], e1 = rp[n + 1];
        float4 arn = *(const float4*)(ar4 + (size_t)n * 4);
        float4 aln = *(const float4*)(al4 + (size_t)n * 4);
        float4 wsf = wexp4(aln, arn);           // self-loop weight
        ushort4 sv = *(const ushort4*)(xw1b + (size_t)n * 256 + lane * 4);
        float a0 = wsf.x * bf2f(sv.x);
        float a1 = wsf.y * bf2f(sv.y);
        float a2 = wsf.z * bf2f(sv.z);
        float a3 = wsf.w * bf2f(sv.w);
        float px = 0.f, py = 0.f, pz = 0.f, pw = 0.f;   // lane-partial weight sums
        for (int cs = e0; cs < e1; cs += CH) {
            int cnt = min(CH, e1 - cs);
            if (lane < cnt) {
                int s = csr[cs + lane];
                float4 A = *(const float4*)(al4 + (size_t)s * 4);
                float4 w = wexp4(A, arn);
                sbuf[wIdx][lane] = s;
                wbuf[wIdx][lane] = w;
                px += w.x; py += w.y; pz += w.z; pw += w.w;
            }
            // drain LDS writes; per-wave LDS is in-order, no block barrier needed
            asm volatile("s_waitcnt lgkmcnt(0)" ::: "memory");
            int jj = 0;
            for (; jj + 4 <= cnt; jj += 4) {
                int s0 = sbuf[wIdx][jj],     s1 = sbuf[wIdx][jj + 1];
                int s2 = sbuf[wIdx][jj + 2], s3 = sbuf[wIdx][jj + 3];
                float4 w0 = wbuf[wIdx][jj],     w1 = wbuf[wIdx][jj + 1];
                float4 w2 = wbuf[wIdx][jj + 2], w3 = wbuf[wIdx][jj + 3];
                ushort4 v0 = *(const ushort4*)(xw1b + (size_t)s0 * 256 + lane * 4);
                ushort4 v1 = *(const ushort4*)(xw1b + (size_t)s1 * 256 + lane * 4);
                ushort4 v2 = *(const ushort4*)(xw1b + (size_t)s2 * 256 + lane * 4);
                ushort4 v3 = *(const ushort4*)(xw1b + (size_t)s3 * 256 + lane * 4);
                a0 += w0.x * bf2f(v0.x) + w1.x * bf2f(v1.x) + w2.x * bf2f(v2.x) + w3.x * bf2f(v3.x);
                a1 += w0.y * bf2f(v0.y) + w1.y * bf2f(v1.y) + w2.y * bf2f(v2.y) + w3.y * bf2f(v3.y);
                a2 += w0.z * bf2f(v0.z) + w1.z * bf2f(v1.z) + w2.z * bf2f(v2.z) + w3.z * bf2f(v3.z);
                a3 += w0.w * bf2f(v0.w) + w1.w * bf2f(v1.w) + w2.w * bf2f(v2.w) + w3.w * bf2f(v3.w);
            }
            for (; jj < cnt; jj++) {
                int s = sbuf[wIdx][jj];
                float4 w = wbuf[wIdx][jj];
                ushort4 v = *(const ushort4*)(xw1b + (size_t)s * 256 + lane * 4);
                a0 += w.x * bf2f(v.x);
                a1 += w.y * bf2f(v.y);
                a2 += w.z * bf2f(v.z);
                a3 += w.w * bf2f(v.w);
            }
        }
        float wx = wave_sum(px) + wsf.x;
        float wy = wave_sum(py) + wsf.y;
        float wz = wave_sum(pz) + wsf.z;
        float ww = wave_sum(pw) + wsf.w;
        hs[wIdx][lane]       = eluf(a0 / wx + b1[lane]);
        hs[wIdx][64 + lane]  = eluf(a1 / wy + b1[64 + lane]);
        hs[wIdx][128 + lane] = eluf(a2 / wz + b1[128 + lane]);
        hs[wIdx][192 + lane] = eluf(a3 / ww + b1[192 + lane]);
    }
    __syncthreads();
    if (act) {
        float acc2 = 0.f;
        #pragma unroll 4
        for (int k = 0; k < 256; k++)
            acc2 += hs[wIdx][k] * W2[(size_t)k * 64 + lane];
        xw2b[(size_t)n * 64 + lane] = f2bf(acc2);
        float sl = wave_sum(acc2 * as2[lane]);
        float sr = wave_sum(acc2 * ad2[lane]);
        if (lane == 0) { al2[n] = sl; ar2[n] = sr; }
    }
}

// ------- layer-2 aggregate: two-phase, 4-deep gather, bf16 rows -----------------
__global__ __launch_bounds__(256, 8) void k_agg2(const int* __restrict__ rp,
                                                 const int* __restrict__ csr,
                                                 const float* __restrict__ al2,
                                                 const float* __restrict__ ar2,
                                                 const ushort_t* __restrict__ xw2b,
                                                 const float* __restrict__ b2,
                                                 float* __restrict__ hout, int N) {
    __shared__ float wbuf[4][CH];
    __shared__ int sbuf[4][CH];
    int wIdx = threadIdx.x >> 6;
    int n = (blockIdx.x * 256 + threadIdx.x) >> 6;
    int lane = threadIdx.x & 63;
    if (n >= N) return;
    int e0 = rp[n], e1 = rp[n + 1];
    float arn = ar2[n];
    float wself = __expf(lrelu(al2[n] + arn));
    float acc = wself * bf2f(xw2b[(size_t)n * 64 + lane]);
    float p = 0.f;
    for (int cs = e0; cs < e1; cs += CH) {
        int cnt = min(CH, e1 - cs);
        if (lane < cnt) {
            int s = csr[cs + lane];
            float w = __expf(lrelu(al2[s] + arn));
            sbuf[wIdx][lane] = s;
            wbuf[wIdx][lane] = w;
            p += w;
        }
        asm volatile("s_waitcnt lgkmcnt(0)" ::: "memory");
        int jj = 0;
        for (; jj + 4 <= cnt; jj += 4) {
            int s0 = sbuf[wIdx][jj],     s1 = sbuf[wIdx][jj + 1];
            int s2 = sbuf[wIdx][jj + 2], s3 = sbuf[wIdx][jj + 3];
            float w0 = wbuf[wIdx][jj],     w1 = wbuf[wIdx][jj + 1];
            float w2 = wbuf[wIdx][jj + 2], w3 = wbuf[wIdx][jj + 3];
            float v0 = bf2f(xw2b[(size_t)s0 * 64 + lane]);
            float v1 = bf2f(xw2b[(size_t)s1 * 64 + lane]);
            float v2 = bf2f(xw2b[(size_t)s2 * 64 + lane]);
            float v3 = bf2f(xw2b[(size_t)s3 * 64 + lane]);
            acc += w0 * v0 + w1 * v1 + w2 * v2 + w3 * v3;
        }
        for (; jj < cnt; jj++) {
            int s = sbuf[wIdx][jj];
            acc += wbuf[wIdx][jj] * bf2f(xw2b[(size_t)s * 64 + lane]);
        }
    }
    float wsum = wave_sum(p) + wself;
    hout[(size_t)n * 64 + lane] = eluf(acc / wsum + b2[lane]);
}

// ------- mean pool (batch sorted, 32 nodes/wave) + logits -----------------------
__global__ __launch_bounds__(256) void k_pool(const float* __restrict__ h2,
                                              const int* __restrict__ batch,
                                              float* __restrict__ pooled,
                                              float* __restrict__ cnt, int N) {
    int wave = (blockIdx.x * 256 + threadIdx.x) >> 6;
    int lane = threadIdx.x & 63;
    int n0 = wave * 32;
    if (n0 >= N) return;
    int n1 = min(n0 + 32, N);
    float acc = 0.f; int cl = 0;
    int curg = batch[n0];
    for (int n = n0; n < n1; n++) {
        int g = batch[n];
        if (g != curg) {
            atomicAdd(&pooled[curg * 64 + lane], acc);
            if (lane == 0) atomicAdd(&cnt[curg], (float)cl);
            acc = 0.f; cl = 0; curg = g;
        }
        acc += h2[(size_t)n * 64 + lane];
        cl++;
    }
    atomicAdd(&pooled[curg * 64 + lane], acc);
    if (lane == 0) atomicAdd(&cnt[curg], (float)cl);
}

__global__ __launch_bounds__(64) void k_logits(const float* __restrict__ pooled,
                                               const float* __restrict__ cnt,
                                               const float* __restrict__ fcW,
                                               const float* __restrict__ fcb,
                                               float* __restrict__ out) {
    int t = threadIdx.x;
    if (t >= NG * 2) return;
    int g = t >> 1, o = t & 1;
    float invc = 1.f / fmaxf(cnt[g], 1.f);
    float s = 0.f;
    for (int c = 0; c < 64; c++)
        s += pooled[g * 64 + c] * invc * fcW[c * 2 + o];
    s += fcb[o];
    out[g * 2 + o] = s;
}

extern "C" void kernel_launch(void* const* d_in, const int* in_sizes, int n_in,
                              void* d_out, int out_size, void* d_ws, size_t ws_size,
                              hipStream_t stream) {
    const float* x     = (const float*)d_in[0];
    const int*   ei    = (const int*)d_in[1];
    const int*   batch = (const int*)d_in[2];
    const float* W1    = (const float*)d_in[3];
    const float* as1   = (const float*)d_in[4];
    const float* ad1   = (const float*)d_in[5];
    const float* b1    = (const float*)d_in[6];
    const float* W2    = (const float*)d_in[7];
    const float* as2   = (const float*)d_in[8];
    const float* ad2   = (const float*)d_in[9];
    const float* b2v   = (const float*)d_in[10];
    const float* fcW   = (const float*)d_in[11];
    const float* fcb   = (const float*)d_in[12];
    float* out = (float*)d_out;

    const int N = in_sizes[2];       // 50000
    const int E = in_sizes[1] / 2;   // 800000
    const size_t nv  = (size_t)N * 64;
    const size_t nv4 = (size_t)N * 256;
    const int SB = (N + 1023) / 1024;

    // workspace layout: bf16 xw1, bf16 xw2, then floats, then ints (~36 MB)
    ushort_t* xw1b = (ushort_t*)d_ws;                      // nv4 ushorts (25.6 MB)
    ushort_t* xw2b   = xw1b + nv4;                         // nv ushorts (6.4 MB)
    float*    al4    = (float*)(xw2b + nv);                // N*4
    float*    ar4    = al4 + (size_t)N * 4;                // N*4
    float*    al2    = ar4 + (size_t)N * 4;                // N
    float*    ar2    = al2 + N;                            // N
    float*    pooled = ar2 + N;                            // 512
    float*    cnt    = pooled + NG * 64;                   // 8
    int*      deg    = (int*)(cnt + 8);                    // N
    int*      rp     = deg + N;                            // N+1
    int*      cur    = rp + N + 1;                         // N
    int*      csr    = cur + N;                            // E
    int*      bsum   = csr + E;                            // SB
    int*      boff   = bsum + 64;                          // SB

    const int gE  = (E + 255) / 256;
    const int gB4 = (N + 3) / 4;
    const int gG1 = (N + 15) / 16;
    const int pw  = (N + 31) / 32;
    const int gP  = (pw * 64 + 255) / 256;

    // ---- CSR build ----
    hipMemsetAsync(deg, 0, (size_t)N * sizeof(int), stream);
    k_hist<<<gE, 256, 0, stream>>>(ei, deg, E);
    k_scanA<<<SB, 256, 0, stream>>>(deg, bsum, N);
    k_scanB<<<1, 64, 0, stream>>>(bsum, boff, rp + N, SB);
    k_scanC<<<SB, 256, 0, stream>>>(deg, boff, rp, cur, N);
    k_fill<<<gE, 256, 0, stream>>>(ei, cur, csr, E);

    // ---- layer 1 ----
    k_gemm1<<<gG1, 256, 0, stream>>>(x, W1, as1, ad1, xw1b, al4, ar4, N);
    k_agg4<<<gB4, 256, 0, stream>>>(rp, csr, al4, ar4, xw1b, b1, W2, as2, ad2,
                                    xw2b, al2, ar2, N);

    // ---- layer 2 ----
    k_agg2<<<gB4, 256, 0, stream>>>(rp, csr, al2, ar2, xw2b, b2v, out, N);

    // ---- pooling + logits ----
    hipMemsetAsync(pooled, 0, (NG * 64 + NG) * sizeof(float), stream);
    k_pool<<<gP, 256, 0, stream>>>(out, batch, pooled, cnt, N);
    k_logits<<<1, 64, 0, stream>>>(pooled, cnt, fcW, fcb, out + nv);
}